// Round 14
// baseline (113.934 us; speedup 1.0000x reference)
//
#include <hip/hip_runtime.h>
#include <hip/hip_bf16.h>
#include <math.h>

#define DD 64
#define NPB 2048          // nodes per batch (N)
#define RTOT 65536        // total node rows B*N

typedef __bf16 bf16;
typedef bf16 bf16x8 __attribute__((ext_vector_type(8)));
typedef float f32x4 __attribute__((ext_vector_type(4)));
typedef short short4v __attribute__((ext_vector_type(4)));

#define COMPILER_FENCE() asm volatile("" ::: "memory")

__device__ __forceinline__ f32x4 mfma16(bf16x8 a, bf16x8 b, f32x4 c) {
  return __builtin_amdgcn_mfma_f32_16x16x32_bf16(a, b, c, 0, 0, 0);
}

// Branchless exact-erf GELU: A&S 7.1.26 (|erf err| <= 1.5e-7).
__device__ __forceinline__ float gelu_fast(float x) {
  float u = fabsf(x) * 0.70710678118654752f;
  float t = __builtin_amdgcn_rcpf(fmaf(0.3275911f, u, 1.0f));
  float p = t * fmaf(t, fmaf(t, fmaf(t, fmaf(t, 1.061405429f, -1.453152027f),
                                     1.421413741f), -0.284496736f), 0.254829592f);
  float e = __expf(-u * u);
  float erfa = fmaf(-p, e, 1.0f);
  float s = copysignf(erfa, x);
  return 0.5f * x * (1.0f + s);
}

// XOR swizzle (16B-slot granularity) within a row: flips elem bits 3..5 by row&7.
__device__ __forceinline__ int swz(int col, int row) {
  return col ^ ((row & 7) << 3);
}

__device__ __forceinline__ bf16x8 ld8(const bf16* p) {
  return *reinterpret_cast<const bf16x8*>(p);
}

// ---- prep: weights -> bf16 transposed into Wsc (R12 k_pe prep branch) ----
// Wsc layout: [0:8192) wm1t[n][k], [8192:16384) wu1t, [16384:20480) wm2t,
// [20480:24576) wu2t, [24576:40960) wrt[v][k]
__global__ void __launch_bounds__(256) k_prep(const float* __restrict__ wm1,
                                              const float* __restrict__ wm2,
                                              const float* __restrict__ wu1,
                                              const float* __restrict__ wu2,
                                              const float* __restrict__ wr,
                                              bf16* __restrict__ Wsc) {
  int gid = blockIdx.x * 256 + threadIdx.x;   // 160 * 256 = 40960
  if (gid < 8192) {
    int n = gid >> 7, k = gid & 127;
    Wsc[gid] = (bf16)wm1[k * 64 + n];
  } else if (gid < 16384) {
    int j = gid - 8192, n = j >> 7, k = j & 127;
    Wsc[gid] = (bf16)wu1[k * 64 + n];
  } else if (gid < 20480) {
    int j = gid - 16384, n = j >> 6, k = j & 63;
    Wsc[gid] = (bf16)wm2[k * 64 + n];
  } else if (gid < 24576) {
    int j = gid - 20480, n = j >> 6, k = j & 63;
    Wsc[gid] = (bf16)wu2[k * 64 + n];
  } else {
    int j = gid - 24576, v = j >> 6, k = j & 63;
    Wsc[gid] = (bf16)wr[k * 256 + v];
  }
}

// ---- embed + round 1 fused: per tile, embed rows rb-1..rb+63 into LDS Hb
// ---- (exact 1-row halo recompute), then the proven round body (Hb-sourced).
__global__ void __launch_bounds__(256) k_er1(const int* __restrict__ x,
                                             const float* __restrict__ emb,
                                             const bf16* __restrict__ Wsc,
                                             const float* __restrict__ bm1,
                                             const float* __restrict__ bm2,
                                             const float* __restrict__ bu1,
                                             const float* __restrict__ bu2,
                                             const float* __restrict__ lng,
                                             const float* __restrict__ lnb,
                                             bf16* __restrict__ hout) {
  __shared__ bf16 W1[2][64 * 128];  // wm1t/wu1t, XOR-swizzled (32 KB)
  __shared__ bf16 Ms[64 * 64];
  __shared__ bf16 Hs[64 * 64];
  __shared__ bf16 Hb[65 * 64];      // h0 tile rows rb-1..rb+63, swizzled (8.1 KB)

  const int tid = threadIdx.x;
  const int lane = tid & 63;
  const int wv = tid >> 6;
  const int l15 = lane & 15;
  const int lhi = lane >> 4;

  for (int i = tid; i < 2048; i += 256) {
    int buf = i >> 10, idx = i & 1023;
    int n = idx >> 4, g = (idx & 15) * 8;
    *reinterpret_cast<bf16x8*>(&W1[buf][n * 128 + swz(g, n)]) =
        ld8(Wsc + buf * 8192 + n * 128 + g);
  }
  bf16x8 fm2[4][2], fu2[4][2];
#pragma unroll
  for (int ct = 0; ct < 4; ++ct)
#pragma unroll
    for (int kt = 0; kt < 2; ++kt) {
      int off = (ct * 16 + l15) * 64 + kt * 32 + lhi * 8;
      fm2[ct][kt] = ld8(Wsc + 16384 + off);
      fu2[ct][kt] = ld8(Wsc + 20480 + off);
    }
  float bm1v[4], bm2v[4], bu1v[4], bu2v[4], lngv[4], lnbv[4];
#pragma unroll
  for (int ct = 0; ct < 4; ++ct) {
    int c = ct * 16 + l15;
    bm1v[ct] = bm1[c]; bm2v[ct] = bm2[c];
    bu1v[ct] = bu1[c]; bu2v[ct] = bu2[c];
    lngv[ct] = lng[c]; lnbv[ct] = lnb[c];
  }

  const int lrow = wv * 16 + l15;
  const int sxr = (lrow & 7) << 3;
  const int sxw = (l15 & 7) << 3;
  const f32x4 fz = {0.f, 0.f, 0.f, 0.f};

  for (int tt = 0; tt < 2; ++tt) {
    const int rowbase = (blockIdx.x * 2 + tt) * 64;

    // ---- embed stage: 65 rows x 64 dims -> Hb (f32 math identical to k_pe) ----
    for (int i = tid; i < 65 * 16; i += 256) {
      int r16 = i >> 4, d0 = (i & 15) * 4;
      int ge = rowbase - 1 + r16;
      int gx = ge < 0 ? 0 : ge;
      const int* xp = x + gx * 4;
      f32x4 s = {0.f, 0.f, 0.f, 0.f};
#pragma unroll
      for (int p = 0; p < 4; ++p)
        s += *reinterpret_cast<const f32x4*>(emb + xp[p] * DD + d0);
      short4v o;
#pragma unroll
      for (int j = 0; j < 4; ++j)
        o[j] = (short)__builtin_bit_cast(unsigned short, (bf16)(s[j] * 0.25f));
      *reinterpret_cast<short4v*>(&Hb[r16 * 64 + swz(d0, r16)]) = o;
    }
    __syncthreads();          // weights (tt=0) + Hb visible

    const int grow = rowbase + lrow;
    const int a = 1 + lrow;            // Hb row of this lane's node
    const int sxa = (a & 7) << 3;

    bf16x8 ah0 = ld8(&Hb[a * 64 + ((lhi * 8) ^ sxa)]);
    bf16x8 ah1 = ld8(&Hb[a * 64 + ((32 + lhi * 8) ^ sxa)]);
    bf16x8 al0, al1;
#pragma unroll
    for (int j = 0; j < 8; ++j) { al0[j] = (bf16)0.f; al1[j] = (bf16)0.f; }
    if ((grow & (NPB - 1)) != 0) {
      int p = a - 1, sxp = (p & 7) << 3;
      al0 = ld8(&Hb[p * 64 + ((lhi * 8) ^ sxp)]);
      al1 = ld8(&Hb[p * 64 + ((32 + lhi * 8) ^ sxp)]);
    }

    f32x4 acc[4];
    // ---- GEMM1 ----
#pragma unroll
    for (int ct = 0; ct < 4; ++ct) acc[ct] = fz;
#pragma unroll
    for (int ct = 0; ct < 4; ++ct) {
      const bf16* wb = &W1[0][(ct * 16 + l15) * 128];
      acc[ct] = mfma16(ah0, ld8(wb + ((lhi * 8) ^ sxw)), acc[ct]);
      acc[ct] = mfma16(ah1, ld8(wb + ((32 + lhi * 8) ^ sxw)), acc[ct]);
      acc[ct] = mfma16(al0, ld8(wb + ((64 + lhi * 8) ^ sxw)), acc[ct]);
      acc[ct] = mfma16(al1, ld8(wb + ((96 + lhi * 8) ^ sxw)), acc[ct]);
    }
#pragma unroll
    for (int ct = 0; ct < 4; ++ct)
#pragma unroll
      for (int r = 0; r < 4; ++r) {
        float g = gelu_fast(acc[ct][r] + bm1v[ct]);
        int row = wv * 16 + lhi * 4 + r;
        Hs[row * 64 + swz(ct * 16 + l15, row)] = (bf16)g;
      }
    COMPILER_FENCE();
    // ---- GEMM2 ----
#pragma unroll
    for (int ct = 0; ct < 4; ++ct) acc[ct] = fz;
    {
      bf16x8 g0 = ld8(&Hs[lrow * 64 + ((lhi * 8) ^ sxr)]);
      bf16x8 g1 = ld8(&Hs[lrow * 64 + ((32 + lhi * 8) ^ sxr)]);
#pragma unroll
      for (int ct = 0; ct < 4; ++ct) {
        acc[ct] = mfma16(g0, fm2[ct][0], acc[ct]);
        acc[ct] = mfma16(g1, fm2[ct][1], acc[ct]);
      }
    }
#pragma unroll
    for (int ct = 0; ct < 4; ++ct)
#pragma unroll
      for (int r = 0; r < 4; ++r) {
        int row = wv * 16 + lhi * 4 + r;
        Ms[row * 64 + swz(ct * 16 + l15, row)] = (bf16)(acc[ct][r] + bm2v[ct]);
      }
    COMPILER_FENCE();
    // ---- GEMM3 ----
#pragma unroll
    for (int ct = 0; ct < 4; ++ct) acc[ct] = fz;
    {
      bf16x8 m0 = ld8(&Ms[lrow * 64 + ((lhi * 8) ^ sxr)]);
      bf16x8 m1 = ld8(&Ms[lrow * 64 + ((32 + lhi * 8) ^ sxr)]);
#pragma unroll
      for (int ct = 0; ct < 4; ++ct) {
        const bf16* wb = &W1[1][(ct * 16 + l15) * 128];
        acc[ct] = mfma16(ah0, ld8(wb + ((lhi * 8) ^ sxw)), acc[ct]);
        acc[ct] = mfma16(ah1, ld8(wb + ((32 + lhi * 8) ^ sxw)), acc[ct]);
        acc[ct] = mfma16(m0, ld8(wb + ((64 + lhi * 8) ^ sxw)), acc[ct]);
        acc[ct] = mfma16(m1, ld8(wb + ((96 + lhi * 8) ^ sxw)), acc[ct]);
      }
    }
    COMPILER_FENCE();
#pragma unroll
    for (int ct = 0; ct < 4; ++ct)
#pragma unroll
      for (int r = 0; r < 4; ++r) {
        float g = gelu_fast(acc[ct][r] + bu1v[ct]);
        int row = wv * 16 + lhi * 4 + r;
        Hs[row * 64 + swz(ct * 16 + l15, row)] = (bf16)g;
      }
    COMPILER_FENCE();
    // ---- GEMM4 ----
#pragma unroll
    for (int ct = 0; ct < 4; ++ct) acc[ct] = fz;
    {
      bf16x8 u0 = ld8(&Hs[lrow * 64 + ((lhi * 8) ^ sxr)]);
      bf16x8 u1 = ld8(&Hs[lrow * 64 + ((32 + lhi * 8) ^ sxr)]);
#pragma unroll
      for (int ct = 0; ct < 4; ++ct) {
        acc[ct] = mfma16(u0, fu2[ct][0], acc[ct]);
        acc[ct] = mfma16(u1, fu2[ct][1], acc[ct]);
      }
    }
    // ---- residual (from Hb, bf16 — same precision as global re-read) + LN ----
    float xv[4][4];
#pragma unroll
    for (int ct = 0; ct < 4; ++ct)
#pragma unroll
      for (int r = 0; r < 4; ++r) {
        int b = 1 + wv * 16 + lhi * 4 + r;
        xv[ct][r] = acc[ct][r] + bu2v[ct] +
                    (float)Hb[b * 64 + swz(ct * 16 + l15, b)];
      }
    float s1[4], s2[4];
#pragma unroll
    for (int r = 0; r < 4; ++r) {
      s1[r] = 0.f; s2[r] = 0.f;
#pragma unroll
      for (int ct = 0; ct < 4; ++ct) { s1[r] += xv[ct][r]; s2[r] += xv[ct][r] * xv[ct][r]; }
    }
#pragma unroll
    for (int off = 1; off < 16; off <<= 1)
#pragma unroll
      for (int r = 0; r < 4; ++r) {
        s1[r] += __shfl_xor(s1[r], off);
        s2[r] += __shfl_xor(s2[r], off);
      }
#pragma unroll
    for (int r = 0; r < 4; ++r) {
      float mu = s1[r] * 0.015625f;
      float var = s2[r] * 0.015625f - mu * mu;
      float rstd = rsqrtf(var + 1e-5f);
      int row = rowbase + wv * 16 + lhi * 4 + r;
#pragma unroll
      for (int ct = 0; ct < 4; ++ct)
        hout[(size_t)row * DD + ct * 16 + l15] =
            (bf16)((xv[ct][r] - mu) * rstd * lngv[ct] + lnbv[ct]);
    }
    __syncthreads();          // all Hb reads done before next tile's embed
  }
}

// ---------------- one message-passing round (R12 verbatim) ----------------
__global__ void __launch_bounds__(256) k_r(const bf16* __restrict__ hin,
                                           bf16* __restrict__ hout,
                                           const bf16* __restrict__ Wsc,
                                           const float* __restrict__ bm1,
                                           const float* __restrict__ bm2,
                                           const float* __restrict__ bu1,
                                           const float* __restrict__ bu2,
                                           const float* __restrict__ lng,
                                           const float* __restrict__ lnb) {
  __shared__ bf16 W1[2][64 * 128];  // wm1t/wu1t, XOR-swizzled
  __shared__ bf16 Ms[64 * 64];
  __shared__ bf16 Hs[64 * 64];

  const int tid = threadIdx.x;
  const int lane = tid & 63;
  const int wv = tid >> 6;
  const int l15 = lane & 15;
  const int lhi = lane >> 4;

  for (int i = tid; i < 2048; i += 256) {
    int buf = i >> 10, idx = i & 1023;
    int n = idx >> 4, g = (idx & 15) * 8;
    *reinterpret_cast<bf16x8*>(&W1[buf][n * 128 + swz(g, n)]) =
        ld8(Wsc + buf * 8192 + n * 128 + g);
  }
  bf16x8 fm2[4][2], fu2[4][2];
#pragma unroll
  for (int ct = 0; ct < 4; ++ct)
#pragma unroll
    for (int kt = 0; kt < 2; ++kt) {
      int off = (ct * 16 + l15) * 64 + kt * 32 + lhi * 8;
      fm2[ct][kt] = ld8(Wsc + 16384 + off);
      fu2[ct][kt] = ld8(Wsc + 20480 + off);
    }
  float bm1v[4], bm2v[4], bu1v[4], bu2v[4], lngv[4], lnbv[4];
#pragma unroll
  for (int ct = 0; ct < 4; ++ct) {
    int c = ct * 16 + l15;
    bm1v[ct] = bm1[c]; bm2v[ct] = bm2[c];
    bu1v[ct] = bu1[c]; bu2v[ct] = bu2[c];
    lngv[ct] = lng[c]; lnbv[ct] = lnb[c];
  }
  __syncthreads();

  const int lrow = wv * 16 + l15;
  const int sxr = (lrow & 7) << 3;
  const int sxw = (l15 & 7) << 3;
  const f32x4 fz = {0.f, 0.f, 0.f, 0.f};

  for (int tt = 0; tt < 2; ++tt) {
    const int rowbase = (blockIdx.x * 2 + tt) * 64;
    const int grow = rowbase + lrow;
    const bf16* hrow = hin + (size_t)grow * DD;

    bf16x8 ah0 = ld8(hrow + lhi * 8);
    bf16x8 ah1 = ld8(hrow + 32 + lhi * 8);
    bf16x8 al0, al1;
#pragma unroll
    for (int j = 0; j < 8; ++j) { al0[j] = (bf16)0.f; al1[j] = (bf16)0.f; }
    if ((grow & (NPB - 1)) != 0) {
      al0 = ld8(hrow - DD + lhi * 8);
      al1 = ld8(hrow - DD + 32 + lhi * 8);
    }

    f32x4 acc[4];
    // ---- GEMM1 ----
#pragma unroll
    for (int ct = 0; ct < 4; ++ct) acc[ct] = fz;
#pragma unroll
    for (int ct = 0; ct < 4; ++ct) {
      const bf16* wb = &W1[0][(ct * 16 + l15) * 128];
      acc[ct] = mfma16(ah0, ld8(wb + ((lhi * 8) ^ sxw)), acc[ct]);
      acc[ct] = mfma16(ah1, ld8(wb + ((32 + lhi * 8) ^ sxw)), acc[ct]);
      acc[ct] = mfma16(al0, ld8(wb + ((64 + lhi * 8) ^ sxw)), acc[ct]);
      acc[ct] = mfma16(al1, ld8(wb + ((96 + lhi * 8) ^ sxw)), acc[ct]);
    }
#pragma unroll
    for (int ct = 0; ct < 4; ++ct)
#pragma unroll
      for (int r = 0; r < 4; ++r) {
        float g = gelu_fast(acc[ct][r] + bm1v[ct]);
        int row = wv * 16 + lhi * 4 + r;
        Hs[row * 64 + swz(ct * 16 + l15, row)] = (bf16)g;
      }
    COMPILER_FENCE();
    // ---- GEMM2 ----
#pragma unroll
    for (int ct = 0; ct < 4; ++ct) acc[ct] = fz;
    {
      bf16x8 g0 = ld8(&Hs[lrow * 64 + ((lhi * 8) ^ sxr)]);
      bf16x8 g1 = ld8(&Hs[lrow * 64 + ((32 + lhi * 8) ^ sxr)]);
#pragma unroll
      for (int ct = 0; ct < 4; ++ct) {
        acc[ct] = mfma16(g0, fm2[ct][0], acc[ct]);
        acc[ct] = mfma16(g1, fm2[ct][1], acc[ct]);
      }
    }
#pragma unroll
    for (int ct = 0; ct < 4; ++ct)
#pragma unroll
      for (int r = 0; r < 4; ++r) {
        int row = wv * 16 + lhi * 4 + r;
        Ms[row * 64 + swz(ct * 16 + l15, row)] = (bf16)(acc[ct][r] + bm2v[ct]);
      }
    COMPILER_FENCE();
    // ---- GEMM3 ----
#pragma unroll
    for (int ct = 0; ct < 4; ++ct) acc[ct] = fz;
    {
      bf16x8 m0 = ld8(&Ms[lrow * 64 + ((lhi * 8) ^ sxr)]);
      bf16x8 m1 = ld8(&Ms[lrow * 64 + ((32 + lhi * 8) ^ sxr)]);
#pragma unroll
      for (int ct = 0; ct < 4; ++ct) {
        const bf16* wb = &W1[1][(ct * 16 + l15) * 128];
        acc[ct] = mfma16(ah0, ld8(wb + ((lhi * 8) ^ sxw)), acc[ct]);
        acc[ct] = mfma16(ah1, ld8(wb + ((32 + lhi * 8) ^ sxw)), acc[ct]);
        acc[ct] = mfma16(m0, ld8(wb + ((64 + lhi * 8) ^ sxw)), acc[ct]);
        acc[ct] = mfma16(m1, ld8(wb + ((96 + lhi * 8) ^ sxw)), acc[ct]);
      }
    }
    COMPILER_FENCE();
#pragma unroll
    for (int ct = 0; ct < 4; ++ct)
#pragma unroll
      for (int r = 0; r < 4; ++r) {
        float g = gelu_fast(acc[ct][r] + bu1v[ct]);
        int row = wv * 16 + lhi * 4 + r;
        Hs[row * 64 + swz(ct * 16 + l15, row)] = (bf16)g;
      }
    COMPILER_FENCE();
    // ---- GEMM4 ----
#pragma unroll
    for (int ct = 0; ct < 4; ++ct) acc[ct] = fz;
    {
      bf16x8 u0 = ld8(&Hs[lrow * 64 + ((lhi * 8) ^ sxr)]);
      bf16x8 u1 = ld8(&Hs[lrow * 64 + ((32 + lhi * 8) ^ sxr)]);
#pragma unroll
      for (int ct = 0; ct < 4; ++ct) {
        acc[ct] = mfma16(u0, fu2[ct][0], acc[ct]);
        acc[ct] = mfma16(u1, fu2[ct][1], acc[ct]);
      }
    }
    // ---- residual + LN ----
    float xv[4][4];
#pragma unroll
    for (int ct = 0; ct < 4; ++ct)
#pragma unroll
      for (int r = 0; r < 4; ++r) {
        int row = rowbase + wv * 16 + lhi * 4 + r;
        xv[ct][r] = acc[ct][r] + bu2v[ct] + (float)hin[(size_t)row * DD + ct * 16 + l15];
      }
    float s1[4], s2[4];
#pragma unroll
    for (int r = 0; r < 4; ++r) {
      s1[r] = 0.f; s2[r] = 0.f;
#pragma unroll
      for (int ct = 0; ct < 4; ++ct) { s1[r] += xv[ct][r]; s2[r] += xv[ct][r] * xv[ct][r]; }
    }
#pragma unroll
    for (int off = 1; off < 16; off <<= 1)
#pragma unroll
      for (int r = 0; r < 4; ++r) {
        s1[r] += __shfl_xor(s1[r], off);
        s2[r] += __shfl_xor(s2[r], off);
      }
#pragma unroll
    for (int r = 0; r < 4; ++r) {
      float mu = s1[r] * 0.015625f;
      float var = s2[r] * 0.015625f - mu * mu;
      float rstd = rsqrtf(var + 1e-5f);
      int row = rowbase + wv * 16 + lhi * 4 + r;
#pragma unroll
      for (int ct = 0; ct < 4; ++ct)
        hout[(size_t)row * DD + ct * 16 + l15] =
            (bf16)((xv[ct][r] - mu) * rstd * lngv[ct] + lnbv[ct]);
    }
  }
}

// ---- round 3 + fused readout (R13 verbatim: load-free burst + prefetch) ----
__global__ void __launch_bounds__(256) k_r3r(const bf16* __restrict__ hin,
                                             const bf16* __restrict__ Wsc,
                                             const float* __restrict__ bm1,
                                             const float* __restrict__ bm2,
                                             const float* __restrict__ bu1,
                                             const float* __restrict__ bu2,
                                             const float* __restrict__ lng,
                                             const float* __restrict__ lnb,
                                             const float* __restrict__ br,
                                             float* __restrict__ out) {
  __shared__ bf16 W1[2][64 * 128];   // 32 KB
  __shared__ bf16 Ms[64 * 64];       // msgs, then reused for h3
  __shared__ bf16 Hs[64 * 64];
  __shared__ bf16 Wt[256 * 64];      // wrt [v][k], XOR-swizzled, 32 KB (80 KB tot)

  const int tid = threadIdx.x;
  const int lane = tid & 63;
  const int wv = tid >> 6;
  const int l15 = lane & 15;
  const int lhi = lane >> 4;

  for (int i = tid; i < 2048; i += 256) {
    int buf = i >> 10, idx = i & 1023;
    int n = idx >> 4, g = (idx & 15) * 8;
    *reinterpret_cast<bf16x8*>(&W1[buf][n * 128 + swz(g, n)]) =
        ld8(Wsc + buf * 8192 + n * 128 + g);
  }
  // stage wrt -> Wt (R6-proven swizzled layout)
  {
    const bf16* wrt = Wsc + 24576;
    for (int i = tid; i < 2048; i += 256) {
      int v = i >> 3, g = (i & 7) * 8;
      *reinterpret_cast<bf16x8*>(&Wt[v * 64 + swz(g, v)]) = ld8(wrt + v * 64 + g);
    }
  }
  bf16x8 fm2[4][2], fu2[4][2];
#pragma unroll
  for (int ct = 0; ct < 4; ++ct)
#pragma unroll
    for (int kt = 0; kt < 2; ++kt) {
      int off = (ct * 16 + l15) * 64 + kt * 32 + lhi * 8;
      fm2[ct][kt] = ld8(Wsc + 16384 + off);
      fu2[ct][kt] = ld8(Wsc + 20480 + off);
    }
  float bm1v[4], bm2v[4], bu1v[4], bu2v[4], lngv[4], lnbv[4];
#pragma unroll
  for (int ct = 0; ct < 4; ++ct) {
    int c = ct * 16 + l15;
    bm1v[ct] = bm1[c]; bm2v[ct] = bm2[c];
    bu1v[ct] = bu1[c]; bu2v[ct] = bu2[c];
    lngv[ct] = lng[c]; lnbv[ct] = lnb[c];
  }
  f32x4 brv[16];                      // bias preload, tile-invariant
#pragma unroll
  for (int vt = 0; vt < 16; ++vt)
    brv[vt] = *reinterpret_cast<const f32x4*>(br + vt * 16 + lhi * 4);
  __syncthreads();

  const int lrow = wv * 16 + l15;
  const int sxr = (lrow & 7) << 3;
  const int sxw = (l15 & 7) << 3;
  const int sxv = (l15 & 7) << 3;    // swizzle key for Wt rows (v = vt*16+l15)
  const f32x4 fz = {0.f, 0.f, 0.f, 0.f};

  bf16x8 pah0, pah1, pal0, pal1;     // tile-1 prefetch (issued before t0 stores)
  float pres[4][4];

#pragma unroll
  for (int tt = 0; tt < 2; ++tt) {
    const int rowbase = (blockIdx.x * 2 + tt) * 64;
    const int grow = rowbase + lrow;
    const bf16* hrow = hin + (size_t)grow * DD;

    bf16x8 ah0, ah1, al0, al1;
    if (tt == 0) {
      ah0 = ld8(hrow + lhi * 8);
      ah1 = ld8(hrow + 32 + lhi * 8);
#pragma unroll
      for (int j = 0; j < 8; ++j) { al0[j] = (bf16)0.f; al1[j] = (bf16)0.f; }
      if ((grow & (NPB - 1)) != 0) {
        al0 = ld8(hrow - DD + lhi * 8);
        al1 = ld8(hrow - DD + 32 + lhi * 8);
      }
    } else {
      ah0 = pah0; ah1 = pah1; al0 = pal0; al1 = pal1;
    }

    f32x4 acc[4];
#pragma unroll
    for (int ct = 0; ct < 4; ++ct) acc[ct] = fz;
#pragma unroll
    for (int ct = 0; ct < 4; ++ct) {
      const bf16* wb = &W1[0][(ct * 16 + l15) * 128];
      acc[ct] = mfma16(ah0, ld8(wb + ((lhi * 8) ^ sxw)), acc[ct]);
      acc[ct] = mfma16(ah1, ld8(wb + ((32 + lhi * 8) ^ sxw)), acc[ct]);
      acc[ct] = mfma16(al0, ld8(wb + ((64 + lhi * 8) ^ sxw)), acc[ct]);
      acc[ct] = mfma16(al1, ld8(wb + ((96 + lhi * 8) ^ sxw)), acc[ct]);
    }
#pragma unroll
    for (int ct = 0; ct < 4; ++ct)
#pragma unroll
      for (int r = 0; r < 4; ++r) {
        float g = gelu_fast(acc[ct][r] + bm1v[ct]);
        int row = wv * 16 + lhi * 4 + r;
        Hs[row * 64 + swz(ct * 16 + l15, row)] = (bf16)g;
      }
    COMPILER_FENCE();
#pragma unroll
    for (int ct = 0; ct < 4; ++ct) acc[ct] = fz;
    {
      bf16x8 g0 = ld8(&Hs[lrow * 64 + ((lhi * 8) ^ sxr)]);
      bf16x8 g1 = ld8(&Hs[lrow * 64 + ((32 + lhi * 8) ^ sxr)]);
#pragma unroll
      for (int ct = 0; ct < 4; ++ct) {
        acc[ct] = mfma16(g0, fm2[ct][0], acc[ct]);
        acc[ct] = mfma16(g1, fm2[ct][1], acc[ct]);
      }
    }
#pragma unroll
    for (int ct = 0; ct < 4; ++ct)
#pragma unroll
      for (int r = 0; r < 4; ++r) {
        int row = wv * 16 + lhi * 4 + r;
        Ms[row * 64 + swz(ct * 16 + l15, row)] = (bf16)(acc[ct][r] + bm2v[ct]);
      }
    COMPILER_FENCE();
#pragma unroll
    for (int ct = 0; ct < 4; ++ct) acc[ct] = fz;
    {
      bf16x8 m0 = ld8(&Ms[lrow * 64 + ((lhi * 8) ^ sxr)]);
      bf16x8 m1 = ld8(&Ms[lrow * 64 + ((32 + lhi * 8) ^ sxr)]);
#pragma unroll
      for (int ct = 0; ct < 4; ++ct) {
        const bf16* wb = &W1[1][(ct * 16 + l15) * 128];
        acc[ct] = mfma16(ah0, ld8(wb + ((lhi * 8) ^ sxw)), acc[ct]);
        acc[ct] = mfma16(ah1, ld8(wb + ((32 + lhi * 8) ^ sxw)), acc[ct]);
        acc[ct] = mfma16(m0, ld8(wb + ((64 + lhi * 8) ^ sxw)), acc[ct]);
        acc[ct] = mfma16(m1, ld8(wb + ((96 + lhi * 8) ^ sxw)), acc[ct]);
      }
    }
    COMPILER_FENCE();
#pragma unroll
    for (int ct = 0; ct < 4; ++ct)
#pragma unroll
      for (int r = 0; r < 4; ++r) {
        float g = gelu_fast(acc[ct][r] + bu1v[ct]);
        int row = wv * 16 + lhi * 4 + r;
        Hs[row * 64 + swz(ct * 16 + l15, row)] = (bf16)g;
      }
    COMPILER_FENCE();
#pragma unroll
    for (int ct = 0; ct < 4; ++ct) acc[ct] = fz;
    {
      bf16x8 u0 = ld8(&Hs[lrow * 64 + ((lhi * 8) ^ sxr)]);
      bf16x8 u1 = ld8(&Hs[lrow * 64 + ((32 + lhi * 8) ^ sxr)]);
#pragma unroll
      for (int ct = 0; ct < 4; ++ct) {
        acc[ct] = mfma16(u0, fu2[ct][0], acc[ct]);
        acc[ct] = mfma16(u1, fu2[ct][1], acc[ct]);
      }
    }
    // ---- residual + LN; h3 -> Ms (own rows; Ms dead after GEMM3) ----
    float xv[4][4];
#pragma unroll
    for (int ct = 0; ct < 4; ++ct)
#pragma unroll
      for (int r = 0; r < 4; ++r) {
        if (tt == 0) {
          int row = rowbase + wv * 16 + lhi * 4 + r;
          xv[ct][r] = acc[ct][r] + bu2v[ct] + (float)hin[(size_t)row * DD + ct * 16 + l15];
        } else {
          xv[ct][r] = acc[ct][r] + bu2v[ct] + pres[ct][r];
        }
      }
    float s1[4], s2[4];
#pragma unroll
    for (int r = 0; r < 4; ++r) {
      s1[r] = 0.f; s2[r] = 0.f;
#pragma unroll
      for (int ct = 0; ct < 4; ++ct) { s1[r] += xv[ct][r]; s2[r] += xv[ct][r] * xv[ct][r]; }
    }
#pragma unroll
    for (int off = 1; off < 16; off <<= 1)
#pragma unroll
      for (int r = 0; r < 4; ++r) {
        s1[r] += __shfl_xor(s1[r], off);
        s2[r] += __shfl_xor(s2[r], off);
      }
#pragma unroll
    for (int r = 0; r < 4; ++r) {
      float mu = s1[r] * 0.015625f;
      float var = s2[r] * 0.015625f - mu * mu;
      float rstd = rsqrtf(var + 1e-5f);
      int row = wv * 16 + lhi * 4 + r;
#pragma unroll
      for (int ct = 0; ct < 4; ++ct)
        Ms[row * 64 + swz(ct * 16 + l15, row)] =
            (bf16)((xv[ct][r] - mu) * rstd * lngv[ct] + lnbv[ct]);
    }
    COMPILER_FENCE();

    // ---- tile-1 global prefetch: issued BEFORE tile-0's store burst ----
    if (tt == 0) {
      const int grow1 = grow + 64;
      const bf16* hrow1 = hin + (size_t)grow1 * DD;
      pah0 = ld8(hrow1 + lhi * 8);
      pah1 = ld8(hrow1 + 32 + lhi * 8);
#pragma unroll
      for (int j = 0; j < 8; ++j) { pal0[j] = (bf16)0.f; pal1[j] = (bf16)0.f; }
      if ((grow1 & (NPB - 1)) != 0) {
        pal0 = ld8(hrow1 - DD + lhi * 8);
        pal1 = ld8(hrow1 - DD + 32 + lhi * 8);
      }
#pragma unroll
      for (int ct = 0; ct < 4; ++ct)
#pragma unroll
        for (int r = 0; r < 4; ++r) {
          int row = rowbase + 64 + wv * 16 + lhi * 4 + r;
          pres[ct][r] = (float)hin[(size_t)row * DD + ct * 16 + l15];
        }
    }

    // ---- fused readout: pure {ds_read, MFMA, store} burst (no global loads) ----
    {
      bf16x8 b0 = ld8(&Ms[lrow * 64 + ((lhi * 8) ^ sxr)]);
      bf16x8 b1 = ld8(&Ms[lrow * 64 + ((32 + lhi * 8) ^ sxr)]);
      const int node = rowbase + lrow;
      float* ob = out + (size_t)node * 1024 + lhi * 4;
#pragma unroll
      for (int vt = 0; vt < 16; ++vt) {
        const bf16* wb = &Wt[(vt * 16 + l15) * 64];
        bf16x8 a0 = ld8(wb + ((lhi * 8) ^ sxv));
        bf16x8 a1 = ld8(wb + ((32 + lhi * 8) ^ sxv));
        f32x4 a = mfma16(a0, b0, brv[vt]);   // bias as C-init
        a = mfma16(a1, b1, a);
        float* p = ob + vt * 16;
#pragma unroll
        for (int rep = 0; rep < 4; ++rep)
          *reinterpret_cast<f32x4*>(p + rep * 256) = a;
      }
    }
    COMPILER_FENCE();   // Ms reads done before next tile overwrites (same wave)
  }
}

extern "C" void kernel_launch(void* const* d_in, const int* in_sizes, int n_in,
                              void* d_out, int out_size, void* d_ws, size_t ws_size,
                              hipStream_t stream) {
  const int*   x   = (const int*)d_in[0];
  const float* emb = (const float*)d_in[1];
  const float* wm1 = (const float*)d_in[2];
  const float* bm1 = (const float*)d_in[3];
  const float* wm2 = (const float*)d_in[4];
  const float* bm2 = (const float*)d_in[5];
  const float* wu1 = (const float*)d_in[6];
  const float* bu1 = (const float*)d_in[7];
  const float* wu2 = (const float*)d_in[8];
  const float* bu2 = (const float*)d_in[9];
  const float* lng = (const float*)d_in[10];
  const float* lnb = (const float*)d_in[11];
  const float* wr  = (const float*)d_in[12];
  const float* br  = (const float*)d_in[13];
  float* out = (float*)d_out;

  char* ws = (char*)d_ws;
  bf16* hA  = (bf16*)ws;                                    // 8 MB
  bf16* hB  = (bf16*)(ws + (size_t)RTOT * DD * 2);          // 8 MB
  bf16* Wsc = (bf16*)(ws + (size_t)RTOT * DD * 4);          // 80 KB @ +16MB

  hipLaunchKernelGGL(k_prep, dim3(160), dim3(256), 0, stream,
                     wm1, wm2, wu1, wu2, wr, Wsc);
  hipLaunchKernelGGL(k_er1, dim3(512), dim3(256), 0, stream,
                     x, emb, Wsc, bm1, bm2, bu1, bu2, lng, lnb, hB);
  hipLaunchKernelGGL(k_r, dim3(512), dim3(256), 0, stream,
                     hB, hA, Wsc, bm1, bm2, bu1, bu2, lng, lnb);
  hipLaunchKernelGGL(k_r3r, dim3(512), dim3(256), 0, stream,
                     hA, Wsc, bm1, bm2, bu1, bu2, lng, lnb, br, out);
}

// Round 15
// 111.918 us; speedup vs baseline: 1.0180x; 1.0180x over previous
//
#include <hip/hip_runtime.h>
#include <hip/hip_bf16.h>
#include <math.h>

#define DD 64
#define NPB 2048          // nodes per batch (N)
#define RTOT 65536        // total node rows B*N

typedef __bf16 bf16;
typedef bf16 bf16x8 __attribute__((ext_vector_type(8)));
typedef float f32x4 __attribute__((ext_vector_type(4)));
typedef short short4v __attribute__((ext_vector_type(4)));

#define COMPILER_FENCE() asm volatile("" ::: "memory")

__device__ __forceinline__ f32x4 mfma16(bf16x8 a, bf16x8 b, f32x4 c) {
  return __builtin_amdgcn_mfma_f32_16x16x32_bf16(a, b, c, 0, 0, 0);
}

// Branchless exact-erf GELU: A&S 7.1.26 (|erf err| <= 1.5e-7).
__device__ __forceinline__ float gelu_fast(float x) {
  float u = fabsf(x) * 0.70710678118654752f;
  float t = __builtin_amdgcn_rcpf(fmaf(0.3275911f, u, 1.0f));
  float p = t * fmaf(t, fmaf(t, fmaf(t, fmaf(t, 1.061405429f, -1.453152027f),
                                     1.421413741f), -0.284496736f), 0.254829592f);
  float e = __expf(-u * u);
  float erfa = fmaf(-p, e, 1.0f);
  float s = copysignf(erfa, x);
  return 0.5f * x * (1.0f + s);
}

// XOR swizzle (16B-slot granularity) within a row: flips elem bits 3..5 by row&7.
__device__ __forceinline__ int swz(int col, int row) {
  return col ^ ((row & 7) << 3);
}

__device__ __forceinline__ bf16x8 ld8(const bf16* p) {
  return *reinterpret_cast<const bf16x8*>(p);
}

// ---- fused prep + embed (R12 verbatim) ----
// Wsc layout: [0:8192) wm1t[n][k], [8192:16384) wu1t, [16384:20480) wm2t,
// [20480:24576) wu2t, [24576:40960) wrt[v][k]
__global__ void __launch_bounds__(256) k_pe(const int* __restrict__ x,
                                            const float* __restrict__ emb,
                                            const float* __restrict__ wm1,
                                            const float* __restrict__ wm2,
                                            const float* __restrict__ wu1,
                                            const float* __restrict__ wu2,
                                            const float* __restrict__ wr,
                                            bf16* __restrict__ Wsc,
                                            bf16* __restrict__ h) {
  const int b = blockIdx.x;
  if (b < 160) {
    int gid = b * 256 + threadIdx.x;   // 160 * 256 = 40960
    if (gid < 8192) {
      int n = gid >> 7, k = gid & 127;
      Wsc[gid] = (bf16)wm1[k * 64 + n];
    } else if (gid < 16384) {
      int j = gid - 8192, n = j >> 7, k = j & 127;
      Wsc[gid] = (bf16)wu1[k * 64 + n];
    } else if (gid < 20480) {
      int j = gid - 16384, n = j >> 6, k = j & 63;
      Wsc[gid] = (bf16)wm2[k * 64 + n];
    } else if (gid < 24576) {
      int j = gid - 20480, n = j >> 6, k = j & 63;
      Wsc[gid] = (bf16)wu2[k * 64 + n];
    } else {
      int j = gid - 24576, v = j >> 6, k = j & 63;
      Wsc[gid] = (bf16)wr[k * 256 + v];
    }
  } else {
    int gid = (b - 160) * 256 + threadIdx.x;   // RTOT*16 threads, 4 dims each
    int row = gid >> 4, d0 = (gid & 15) * 4;
    const int* xp = x + row * 4;
    f32x4 s = {0.f, 0.f, 0.f, 0.f};
#pragma unroll
    for (int p = 0; p < 4; ++p)
      s += *reinterpret_cast<const f32x4*>(emb + xp[p] * DD + d0);
    short4v o;
#pragma unroll
    for (int j = 0; j < 4; ++j)
      o[j] = (short)__builtin_bit_cast(unsigned short, (bf16)(s[j] * 0.25f));
    *reinterpret_cast<short4v*>(h + row * DD + d0) = o;
  }
}

// ---------------- one message-passing round (R12 verbatim) ----------------
__global__ void __launch_bounds__(256) k_r(const bf16* __restrict__ hin,
                                           bf16* __restrict__ hout,
                                           const bf16* __restrict__ Wsc,
                                           const float* __restrict__ bm1,
                                           const float* __restrict__ bm2,
                                           const float* __restrict__ bu1,
                                           const float* __restrict__ bu2,
                                           const float* __restrict__ lng,
                                           const float* __restrict__ lnb) {
  __shared__ bf16 W1[2][64 * 128];  // wm1t/wu1t, XOR-swizzled
  __shared__ bf16 Ms[64 * 64];
  __shared__ bf16 Hs[64 * 64];

  const int tid = threadIdx.x;
  const int lane = tid & 63;
  const int wv = tid >> 6;
  const int l15 = lane & 15;
  const int lhi = lane >> 4;

  for (int i = tid; i < 2048; i += 256) {
    int buf = i >> 10, idx = i & 1023;
    int n = idx >> 4, g = (idx & 15) * 8;
    *reinterpret_cast<bf16x8*>(&W1[buf][n * 128 + swz(g, n)]) =
        ld8(Wsc + buf * 8192 + n * 128 + g);
  }
  bf16x8 fm2[4][2], fu2[4][2];
#pragma unroll
  for (int ct = 0; ct < 4; ++ct)
#pragma unroll
    for (int kt = 0; kt < 2; ++kt) {
      int off = (ct * 16 + l15) * 64 + kt * 32 + lhi * 8;
      fm2[ct][kt] = ld8(Wsc + 16384 + off);
      fu2[ct][kt] = ld8(Wsc + 20480 + off);
    }
  float bm1v[4], bm2v[4], bu1v[4], bu2v[4], lngv[4], lnbv[4];
#pragma unroll
  for (int ct = 0; ct < 4; ++ct) {
    int c = ct * 16 + l15;
    bm1v[ct] = bm1[c]; bm2v[ct] = bm2[c];
    bu1v[ct] = bu1[c]; bu2v[ct] = bu2[c];
    lngv[ct] = lng[c]; lnbv[ct] = lnb[c];
  }
  __syncthreads();

  const int lrow = wv * 16 + l15;
  const int sxr = (lrow & 7) << 3;
  const int sxw = (l15 & 7) << 3;
  const f32x4 fz = {0.f, 0.f, 0.f, 0.f};

  for (int tt = 0; tt < 2; ++tt) {
    const int rowbase = (blockIdx.x * 2 + tt) * 64;
    const int grow = rowbase + lrow;
    const bf16* hrow = hin + (size_t)grow * DD;

    bf16x8 ah0 = ld8(hrow + lhi * 8);
    bf16x8 ah1 = ld8(hrow + 32 + lhi * 8);
    bf16x8 al0, al1;
#pragma unroll
    for (int j = 0; j < 8; ++j) { al0[j] = (bf16)0.f; al1[j] = (bf16)0.f; }
    if ((grow & (NPB - 1)) != 0) {
      al0 = ld8(hrow - DD + lhi * 8);
      al1 = ld8(hrow - DD + 32 + lhi * 8);
    }

    f32x4 acc[4];
    // ---- GEMM1 ----
#pragma unroll
    for (int ct = 0; ct < 4; ++ct) acc[ct] = fz;
#pragma unroll
    for (int ct = 0; ct < 4; ++ct) {
      const bf16* wb = &W1[0][(ct * 16 + l15) * 128];
      acc[ct] = mfma16(ah0, ld8(wb + ((lhi * 8) ^ sxw)), acc[ct]);
      acc[ct] = mfma16(ah1, ld8(wb + ((32 + lhi * 8) ^ sxw)), acc[ct]);
      acc[ct] = mfma16(al0, ld8(wb + ((64 + lhi * 8) ^ sxw)), acc[ct]);
      acc[ct] = mfma16(al1, ld8(wb + ((96 + lhi * 8) ^ sxw)), acc[ct]);
    }
#pragma unroll
    for (int ct = 0; ct < 4; ++ct)
#pragma unroll
      for (int r = 0; r < 4; ++r) {
        float g = gelu_fast(acc[ct][r] + bm1v[ct]);
        int row = wv * 16 + lhi * 4 + r;
        Hs[row * 64 + swz(ct * 16 + l15, row)] = (bf16)g;
      }
    COMPILER_FENCE();
    // ---- GEMM2 ----
#pragma unroll
    for (int ct = 0; ct < 4; ++ct) acc[ct] = fz;
    {
      bf16x8 g0 = ld8(&Hs[lrow * 64 + ((lhi * 8) ^ sxr)]);
      bf16x8 g1 = ld8(&Hs[lrow * 64 + ((32 + lhi * 8) ^ sxr)]);
#pragma unroll
      for (int ct = 0; ct < 4; ++ct) {
        acc[ct] = mfma16(g0, fm2[ct][0], acc[ct]);
        acc[ct] = mfma16(g1, fm2[ct][1], acc[ct]);
      }
    }
#pragma unroll
    for (int ct = 0; ct < 4; ++ct)
#pragma unroll
      for (int r = 0; r < 4; ++r) {
        int row = wv * 16 + lhi * 4 + r;
        Ms[row * 64 + swz(ct * 16 + l15, row)] = (bf16)(acc[ct][r] + bm2v[ct]);
      }
    COMPILER_FENCE();
    // ---- GEMM3 ----
#pragma unroll
    for (int ct = 0; ct < 4; ++ct) acc[ct] = fz;
    {
      bf16x8 m0 = ld8(&Ms[lrow * 64 + ((lhi * 8) ^ sxr)]);
      bf16x8 m1 = ld8(&Ms[lrow * 64 + ((32 + lhi * 8) ^ sxr)]);
#pragma unroll
      for (int ct = 0; ct < 4; ++ct) {
        const bf16* wb = &W1[1][(ct * 16 + l15) * 128];
        acc[ct] = mfma16(ah0, ld8(wb + ((lhi * 8) ^ sxw)), acc[ct]);
        acc[ct] = mfma16(ah1, ld8(wb + ((32 + lhi * 8) ^ sxw)), acc[ct]);
        acc[ct] = mfma16(m0, ld8(wb + ((64 + lhi * 8) ^ sxw)), acc[ct]);
        acc[ct] = mfma16(m1, ld8(wb + ((96 + lhi * 8) ^ sxw)), acc[ct]);
      }
    }
    COMPILER_FENCE();
#pragma unroll
    for (int ct = 0; ct < 4; ++ct)
#pragma unroll
      for (int r = 0; r < 4; ++r) {
        float g = gelu_fast(acc[ct][r] + bu1v[ct]);
        int row = wv * 16 + lhi * 4 + r;
        Hs[row * 64 + swz(ct * 16 + l15, row)] = (bf16)g;
      }
    COMPILER_FENCE();
    // ---- GEMM4 ----
#pragma unroll
    for (int ct = 0; ct < 4; ++ct) acc[ct] = fz;
    {
      bf16x8 u0 = ld8(&Hs[lrow * 64 + ((lhi * 8) ^ sxr)]);
      bf16x8 u1 = ld8(&Hs[lrow * 64 + ((32 + lhi * 8) ^ sxr)]);
#pragma unroll
      for (int ct = 0; ct < 4; ++ct) {
        acc[ct] = mfma16(u0, fu2[ct][0], acc[ct]);
        acc[ct] = mfma16(u1, fu2[ct][1], acc[ct]);
      }
    }
    // ---- residual + LN ----
    float xv[4][4];
#pragma unroll
    for (int ct = 0; ct < 4; ++ct)
#pragma unroll
      for (int r = 0; r < 4; ++r) {
        int row = rowbase + wv * 16 + lhi * 4 + r;
        xv[ct][r] = acc[ct][r] + bu2v[ct] + (float)hin[(size_t)row * DD + ct * 16 + l15];
      }
    float s1[4], s2[4];
#pragma unroll
    for (int r = 0; r < 4; ++r) {
      s1[r] = 0.f; s2[r] = 0.f;
#pragma unroll
      for (int ct = 0; ct < 4; ++ct) { s1[r] += xv[ct][r]; s2[r] += xv[ct][r] * xv[ct][r]; }
    }
#pragma unroll
    for (int off = 1; off < 16; off <<= 1)
#pragma unroll
      for (int r = 0; r < 4; ++r) {
        s1[r] += __shfl_xor(s1[r], off);
        s2[r] += __shfl_xor(s2[r], off);
      }
#pragma unroll
    for (int r = 0; r < 4; ++r) {
      float mu = s1[r] * 0.015625f;
      float var = s2[r] * 0.015625f - mu * mu;
      float rstd = rsqrtf(var + 1e-5f);
      int row = rowbase + wv * 16 + lhi * 4 + r;
#pragma unroll
      for (int ct = 0; ct < 4; ++ct)
        hout[(size_t)row * DD + ct * 16 + l15] =
            (bf16)((xv[ct][r] - mu) * rstd * lngv[ct] + lnbv[ct]);
    }
  }
}

// ---- round 3 + fused readout: load-free store burst + tile-1 prefetch ----
__global__ void __launch_bounds__(256) k_r3r(const bf16* __restrict__ hin,
                                             const bf16* __restrict__ Wsc,
                                             const float* __restrict__ bm1,
                                             const float* __restrict__ bm2,
                                             const float* __restrict__ bu1,
                                             const float* __restrict__ bu2,
                                             const float* __restrict__ lng,
                                             const float* __restrict__ lnb,
                                             const float* __restrict__ br,
                                             float* __restrict__ out) {
  __shared__ bf16 W1[2][64 * 128];   // 32 KB
  __shared__ bf16 Ms[64 * 64];       // msgs, then reused for h3
  __shared__ bf16 Hs[64 * 64];
  __shared__ bf16 Wt[256 * 64];      // wrt [v][k], XOR-swizzled, 32 KB (80 KB tot)

  const int tid = threadIdx.x;
  const int lane = tid & 63;
  const int wv = tid >> 6;
  const int l15 = lane & 15;
  const int lhi = lane >> 4;

  for (int i = tid; i < 2048; i += 256) {
    int buf = i >> 10, idx = i & 1023;
    int n = idx >> 4, g = (idx & 15) * 8;
    *reinterpret_cast<bf16x8*>(&W1[buf][n * 128 + swz(g, n)]) =
        ld8(Wsc + buf * 8192 + n * 128 + g);
  }
  // stage wrt -> Wt (R6-proven swizzled layout)
  {
    const bf16* wrt = Wsc + 24576;
    for (int i = tid; i < 2048; i += 256) {
      int v = i >> 3, g = (i & 7) * 8;
      *reinterpret_cast<bf16x8*>(&Wt[v * 64 + swz(g, v)]) = ld8(wrt + v * 64 + g);
    }
  }
  bf16x8 fm2[4][2], fu2[4][2];
#pragma unroll
  for (int ct = 0; ct < 4; ++ct)
#pragma unroll
    for (int kt = 0; kt < 2; ++kt) {
      int off = (ct * 16 + l15) * 64 + kt * 32 + lhi * 8;
      fm2[ct][kt] = ld8(Wsc + 16384 + off);
      fu2[ct][kt] = ld8(Wsc + 20480 + off);
    }
  float bm1v[4], bm2v[4], bu1v[4], bu2v[4], lngv[4], lnbv[4];
#pragma unroll
  for (int ct = 0; ct < 4; ++ct) {
    int c = ct * 16 + l15;
    bm1v[ct] = bm1[c]; bm2v[ct] = bm2[c];
    bu1v[ct] = bu1[c]; bu2v[ct] = bu2[c];
    lngv[ct] = lng[c]; lnbv[ct] = lnb[c];
  }
  f32x4 brv[16];                      // bias preload, tile-invariant
#pragma unroll
  for (int vt = 0; vt < 16; ++vt)
    brv[vt] = *reinterpret_cast<const f32x4*>(br + vt * 16 + lhi * 4);
  __syncthreads();

  const int lrow = wv * 16 + l15;
  const int sxr = (lrow & 7) << 3;
  const int sxw = (l15 & 7) << 3;
  const int sxv = (l15 & 7) << 3;    // swizzle key for Wt rows (v = vt*16+l15)
  const f32x4 fz = {0.f, 0.f, 0.f, 0.f};

  bf16x8 pah0, pah1, pal0, pal1;     // tile-1 prefetch (issued before t0 stores)
  float pres[4][4];

#pragma unroll
  for (int tt = 0; tt < 2; ++tt) {
    const int rowbase = (blockIdx.x * 2 + tt) * 64;
    const int grow = rowbase + lrow;
    const bf16* hrow = hin + (size_t)grow * DD;

    bf16x8 ah0, ah1, al0, al1;
    if (tt == 0) {
      ah0 = ld8(hrow + lhi * 8);
      ah1 = ld8(hrow + 32 + lhi * 8);
#pragma unroll
      for (int j = 0; j < 8; ++j) { al0[j] = (bf16)0.f; al1[j] = (bf16)0.f; }
      if ((grow & (NPB - 1)) != 0) {
        al0 = ld8(hrow - DD + lhi * 8);
        al1 = ld8(hrow - DD + 32 + lhi * 8);
      }
    } else {
      ah0 = pah0; ah1 = pah1; al0 = pal0; al1 = pal1;
    }

    f32x4 acc[4];
#pragma unroll
    for (int ct = 0; ct < 4; ++ct) acc[ct] = fz;
#pragma unroll
    for (int ct = 0; ct < 4; ++ct) {
      const bf16* wb = &W1[0][(ct * 16 + l15) * 128];
      acc[ct] = mfma16(ah0, ld8(wb + ((lhi * 8) ^ sxw)), acc[ct]);
      acc[ct] = mfma16(ah1, ld8(wb + ((32 + lhi * 8) ^ sxw)), acc[ct]);
      acc[ct] = mfma16(al0, ld8(wb + ((64 + lhi * 8) ^ sxw)), acc[ct]);
      acc[ct] = mfma16(al1, ld8(wb + ((96 + lhi * 8) ^ sxw)), acc[ct]);
    }
#pragma unroll
    for (int ct = 0; ct < 4; ++ct)
#pragma unroll
      for (int r = 0; r < 4; ++r) {
        float g = gelu_fast(acc[ct][r] + bm1v[ct]);
        int row = wv * 16 + lhi * 4 + r;
        Hs[row * 64 + swz(ct * 16 + l15, row)] = (bf16)g;
      }
    COMPILER_FENCE();
#pragma unroll
    for (int ct = 0; ct < 4; ++ct) acc[ct] = fz;
    {
      bf16x8 g0 = ld8(&Hs[lrow * 64 + ((lhi * 8) ^ sxr)]);
      bf16x8 g1 = ld8(&Hs[lrow * 64 + ((32 + lhi * 8) ^ sxr)]);
#pragma unroll
      for (int ct = 0; ct < 4; ++ct) {
        acc[ct] = mfma16(g0, fm2[ct][0], acc[ct]);
        acc[ct] = mfma16(g1, fm2[ct][1], acc[ct]);
      }
    }
#pragma unroll
    for (int ct = 0; ct < 4; ++ct)
#pragma unroll
      for (int r = 0; r < 4; ++r) {
        int row = wv * 16 + lhi * 4 + r;
        Ms[row * 64 + swz(ct * 16 + l15, row)] = (bf16)(acc[ct][r] + bm2v[ct]);
      }
    COMPILER_FENCE();
#pragma unroll
    for (int ct = 0; ct < 4; ++ct) acc[ct] = fz;
    {
      bf16x8 m0 = ld8(&Ms[lrow * 64 + ((lhi * 8) ^ sxr)]);
      bf16x8 m1 = ld8(&Ms[lrow * 64 + ((32 + lhi * 8) ^ sxr)]);
#pragma unroll
      for (int ct = 0; ct < 4; ++ct) {
        const bf16* wb = &W1[1][(ct * 16 + l15) * 128];
        acc[ct] = mfma16(ah0, ld8(wb + ((lhi * 8) ^ sxw)), acc[ct]);
        acc[ct] = mfma16(ah1, ld8(wb + ((32 + lhi * 8) ^ sxw)), acc[ct]);
        acc[ct] = mfma16(m0, ld8(wb + ((64 + lhi * 8) ^ sxw)), acc[ct]);
        acc[ct] = mfma16(m1, ld8(wb + ((96 + lhi * 8) ^ sxw)), acc[ct]);
      }
    }
    COMPILER_FENCE();
#pragma unroll
    for (int ct = 0; ct < 4; ++ct)
#pragma unroll
      for (int r = 0; r < 4; ++r) {
        float g = gelu_fast(acc[ct][r] + bu1v[ct]);
        int row = wv * 16 + lhi * 4 + r;
        Hs[row * 64 + swz(ct * 16 + l15, row)] = (bf16)g;
      }
    COMPILER_FENCE();
#pragma unroll
    for (int ct = 0; ct < 4; ++ct) acc[ct] = fz;
    {
      bf16x8 u0 = ld8(&Hs[lrow * 64 + ((lhi * 8) ^ sxr)]);
      bf16x8 u1 = ld8(&Hs[lrow * 64 + ((32 + lhi * 8) ^ sxr)]);
#pragma unroll
      for (int ct = 0; ct < 4; ++ct) {
        acc[ct] = mfma16(u0, fu2[ct][0], acc[ct]);
        acc[ct] = mfma16(u1, fu2[ct][1], acc[ct]);
      }
    }
    // ---- residual + LN; h3 -> Ms (own rows; Ms dead after GEMM3) ----
    float xv[4][4];
#pragma unroll
    for (int ct = 0; ct < 4; ++ct)
#pragma unroll
      for (int r = 0; r < 4; ++r) {
        if (tt == 0) {
          int row = rowbase + wv * 16 + lhi * 4 + r;
          xv[ct][r] = acc[ct][r] + bu2v[ct] + (float)hin[(size_t)row * DD + ct * 16 + l15];
        } else {
          xv[ct][r] = acc[ct][r] + bu2v[ct] + pres[ct][r];
        }
      }
    float s1[4], s2[4];
#pragma unroll
    for (int r = 0; r < 4; ++r) {
      s1[r] = 0.f; s2[r] = 0.f;
#pragma unroll
      for (int ct = 0; ct < 4; ++ct) { s1[r] += xv[ct][r]; s2[r] += xv[ct][r] * xv[ct][r]; }
    }
#pragma unroll
    for (int off = 1; off < 16; off <<= 1)
#pragma unroll
      for (int r = 0; r < 4; ++r) {
        s1[r] += __shfl_xor(s1[r], off);
        s2[r] += __shfl_xor(s2[r], off);
      }
#pragma unroll
    for (int r = 0; r < 4; ++r) {
      float mu = s1[r] * 0.015625f;
      float var = s2[r] * 0.015625f - mu * mu;
      float rstd = rsqrtf(var + 1e-5f);
      int row = wv * 16 + lhi * 4 + r;
#pragma unroll
      for (int ct = 0; ct < 4; ++ct)
        Ms[row * 64 + swz(ct * 16 + l15, row)] =
            (bf16)((xv[ct][r] - mu) * rstd * lngv[ct] + lnbv[ct]);
    }
    COMPILER_FENCE();

    // ---- tile-1 global prefetch: issued BEFORE tile-0's store burst ----
    if (tt == 0) {
      const int grow1 = grow + 64;
      const bf16* hrow1 = hin + (size_t)grow1 * DD;
      pah0 = ld8(hrow1 + lhi * 8);
      pah1 = ld8(hrow1 + 32 + lhi * 8);
#pragma unroll
      for (int j = 0; j < 8; ++j) { pal0[j] = (bf16)0.f; pal1[j] = (bf16)0.f; }
      if ((grow1 & (NPB - 1)) != 0) {
        pal0 = ld8(hrow1 - DD + lhi * 8);
        pal1 = ld8(hrow1 - DD + 32 + lhi * 8);
      }
#pragma unroll
      for (int ct = 0; ct < 4; ++ct)
#pragma unroll
        for (int r = 0; r < 4; ++r) {
          int row = rowbase + 64 + wv * 16 + lhi * 4 + r;
          pres[ct][r] = (float)hin[(size_t)row * DD + ct * 16 + l15];
        }
    }

    // ---- fused readout: pure {ds_read, MFMA, store} burst (no global loads) ----
    {
      bf16x8 b0 = ld8(&Ms[lrow * 64 + ((lhi * 8) ^ sxr)]);
      bf16x8 b1 = ld8(&Ms[lrow * 64 + ((32 + lhi * 8) ^ sxr)]);
      const int node = rowbase + lrow;
      float* ob = out + (size_t)node * 1024 + lhi * 4;
#pragma unroll
      for (int vt = 0; vt < 16; ++vt) {
        const bf16* wb = &Wt[(vt * 16 + l15) * 64];
        bf16x8 a0 = ld8(wb + ((lhi * 8) ^ sxv));
        bf16x8 a1 = ld8(wb + ((32 + lhi * 8) ^ sxv));
        f32x4 a = mfma16(a0, b0, brv[vt]);   // bias as C-init
        a = mfma16(a1, b1, a);
        float* p = ob + vt * 16;
#pragma unroll
        for (int rep = 0; rep < 4; ++rep)
          *reinterpret_cast<f32x4*>(p + rep * 256) = a;
      }
    }
    COMPILER_FENCE();   // Ms reads done before next tile overwrites (same wave)
  }
}

extern "C" void kernel_launch(void* const* d_in, const int* in_sizes, int n_in,
                              void* d_out, int out_size, void* d_ws, size_t ws_size,
                              hipStream_t stream) {
  const int*   x   = (const int*)d_in[0];
  const float* emb = (const float*)d_in[1];
  const float* wm1 = (const float*)d_in[2];
  const float* bm1 = (const float*)d_in[3];
  const float* wm2 = (const float*)d_in[4];
  const float* bm2 = (const float*)d_in[5];
  const float* wu1 = (const float*)d_in[6];
  const float* bu1 = (const float*)d_in[7];
  const float* wu2 = (const float*)d_in[8];
  const float* bu2 = (const float*)d_in[9];
  const float* lng = (const float*)d_in[10];
  const float* lnb = (const float*)d_in[11];
  const float* wr  = (const float*)d_in[12];
  const float* br  = (const float*)d_in[13];
  float* out = (float*)d_out;

  char* ws = (char*)d_ws;
  bf16* hA  = (bf16*)ws;                                    // 8 MB
  bf16* hB  = (bf16*)(ws + (size_t)RTOT * DD * 2);          // 8 MB
  bf16* Wsc = (bf16*)(ws + (size_t)RTOT * DD * 4);          // 80 KB @ +16MB

  hipLaunchKernelGGL(k_pe, dim3(4256), dim3(256), 0, stream,
                     x, emb, wm1, wm2, wu1, wu2, wr, Wsc, hA);
  hipLaunchKernelGGL(k_r, dim3(512), dim3(256), 0, stream,
                     hA, hB, Wsc, bm1, bm2, bu1, bu2, lng, lnb);
  hipLaunchKernelGGL(k_r, dim3(512), dim3(256), 0, stream,
                     hB, hA, Wsc, bm1, bm2, bu1, bu2, lng, lnb);
  hipLaunchKernelGGL(k_r3r, dim3(512), dim3(256), 0, stream,
                     hA, Wsc, bm1, bm2, bu1, bu2, lng, lnb, br, out);
}